// Round 10
// baseline (169.273 us; speedup 1.0000x reference)
//
#include <hip/hip_runtime.h>

#define HIDDEN 256
#define GAMMA_F 12.0f
#define BATCH 8

// ---------------------------------------------------------------------------
// Kernel A: stream the entity table once; PLANAR output dist[b][e].
// Lane covers dims [4*lane, 4*lane+4): one float4 load inst = one full 1KB
// row, unique + contiguous. Per row: merge-tree (offsets 1,2,4 fold the 3
// batch bits into lane bits 0..2, offsets 8,16,32 butterfly) -> lane l holds
// the complete sum for batch l&7. 8 rows per group: row r latches into lanes
// with (lane>>3)==r, then ONE ds_bpermute transposes so lane l = (b=l>>3,
// r=l&7), giving a single full-wave store: 8 planes x 32B contiguous.
// (Five structurally different variants of this kernel all timed ~45us —
// it is clamped by the harness's L3 write-drain, so keep it simple.)
// ---------------------------------------------------------------------------
__global__ __launch_bounds__(256, 8) void kge_dist_kernel(
    const float* __restrict__ ent,
    const float* __restrict__ rel,
    const int*  __restrict__ pos,
    float* __restrict__ dist,   // [BATCH][nent] planar
    int ngroups, int nent, int nwaves)
{
    const int lane = threadIdx.x & 63;
    const int wave_gid = (blockIdx.x * 256 + threadIdx.x) >> 6;

    // hr[b] = head_b + rel_b at dims [4*lane, 4*lane+4) — 32 VGPRs, once
    float4 hr[BATCH];
    #pragma unroll
    for (int b = 0; b < BATCH; ++b) {
        const int hidx = pos[b * 3 + 0];
        const int ridx = pos[b * 3 + 1];
        const float4 h4 = *(const float4*)(ent + (size_t)hidx * HIDDEN + lane * 4);
        const float4 r4 = *(const float4*)(rel + (size_t)ridx * HIDDEN + lane * 4);
        hr[b] = make_float4(h4.x + r4.x, h4.y + r4.y, h4.z + r4.z, h4.w + r4.w);
    }

    for (int grp = wave_gid; grp < ngroups; grp += nwaves) {
        const int e0 = grp * 8;
        float res = 0.0f;

        #pragma unroll
        for (int r = 0; r < 8; ++r) {
            const float4 t4 =
                *(const float4*)(ent + (size_t)(e0 + r) * HIDDEN + lane * 4);

            float acc[BATCH];
            #pragma unroll
            for (int b = 0; b < BATCH; ++b) {
                acc[b] = fabsf(hr[b].x - t4.x) + fabsf(hr[b].y - t4.y)
                       + fabsf(hr[b].z - t4.z) + fabsf(hr[b].w - t4.w);
            }
            // fold batch bits into lane bits 0..2
            float v[4];
            {
                const bool p = lane & 1;
                #pragma unroll
                for (int k = 0; k < 4; ++k) {
                    const float keep = p ? acc[2 * k + 1] : acc[2 * k];
                    const float give = p ? acc[2 * k]     : acc[2 * k + 1];
                    v[k] = keep + __shfl_xor(give, 1, 64);
                }
            }
            float w2[2];
            {
                const bool p = (lane >> 1) & 1;
                #pragma unroll
                for (int k = 0; k < 2; ++k) {
                    const float keep = p ? v[2 * k + 1] : v[2 * k];
                    const float give = p ? v[2 * k]     : v[2 * k + 1];
                    w2[k] = keep + __shfl_xor(give, 2, 64);
                }
            }
            float s;
            {
                const bool p = (lane >> 2) & 1;
                const float keep = p ? w2[1] : w2[0];
                const float give = p ? w2[0] : w2[1];
                s = keep + __shfl_xor(give, 4, 64);
            }
            s += __shfl_xor(s, 8, 64);
            s += __shfl_xor(s, 16, 64);
            s += __shfl_xor(s, 32, 64);
            // lane l holds batch l&7; latch row r into lanes (l>>3)==r
            if ((lane >> 3) == r) res = GAMMA_F - s;
        }

        // transpose: lane l pulls from lane (l&7)*8 + (l>>3)
        // -> lane l = (b = l>>3, r = l&7); one full-wave planar store
        const int src = ((lane & 7) * 8 + (lane >> 3)) * 4;
        const float val =
            __int_as_float(__builtin_amdgcn_ds_bpermute(src, __float_as_int(res)));
        dist[(size_t)(lane >> 3) * nent + e0 + (lane & 7)] = val;
    }

    // tail rows (none at nent=100000)
    if (wave_gid == 0) {
        for (int e = ngroups * 8; e < nent; ++e) {
            const float4 t4 = *(const float4*)(ent + (size_t)e * HIDDEN + lane * 4);
            float acc[BATCH];
            #pragma unroll
            for (int b = 0; b < BATCH; ++b) {
                acc[b] = fabsf(hr[b].x - t4.x) + fabsf(hr[b].y - t4.y)
                       + fabsf(hr[b].z - t4.z) + fabsf(hr[b].w - t4.w);
            }
            float v[4];
            {
                const bool p = lane & 1;
                #pragma unroll
                for (int k = 0; k < 4; ++k) {
                    const float keep = p ? acc[2 * k + 1] : acc[2 * k];
                    const float give = p ? acc[2 * k]     : acc[2 * k + 1];
                    v[k] = keep + __shfl_xor(give, 1, 64);
                }
            }
            float w2[2];
            {
                const bool p = (lane >> 1) & 1;
                #pragma unroll
                for (int k = 0; k < 2; ++k) {
                    const float keep = p ? v[2 * k + 1] : v[2 * k];
                    const float give = p ? v[2 * k]     : v[2 * k + 1];
                    w2[k] = keep + __shfl_xor(give, 2, 64);
                }
            }
            float s;
            {
                const bool p = (lane >> 2) & 1;
                const float keep = p ? w2[1] : w2[0];
                const float give = p ? w2[0] : w2[1];
                s = keep + __shfl_xor(give, 4, 64);
            }
            s += __shfl_xor(s, 8, 64);
            s += __shfl_xor(s, 16, 64);
            s += __shfl_xor(s, 32, 64);
            if (lane < BATCH) dist[(size_t)lane * nent + e] = GAMMA_F - s;
        }
    }
}

// ---------------------------------------------------------------------------
// Kernel B: out[b,n] = dist[b][neg[b,n]]. Plane b is 400KB: each 64B line
// holds 16 candidates for THIS b -> ~16x line reuse, L1/L2-resident gathers.
// 4 outputs/thread: int4 index load, 4 independent gathers, float4 store.
// ---------------------------------------------------------------------------
__global__ __launch_bounds__(256) void kge_gather_kernel(
    const int*  __restrict__ neg,
    const float* __restrict__ dist,
    float* __restrict__ out,
    int nneg, int nent)
{
    const int b = blockIdx.y;
    const float* plane = dist + (size_t)b * nent;
    const int n = (blockIdx.x * 256 + threadIdx.x) * 4;
    if (n + 3 < nneg) {
        const int4 idx = *(const int4*)(neg + (size_t)b * nneg + n);
        float4 r;
        r.x = plane[idx.x];
        r.y = plane[idx.y];
        r.z = plane[idx.z];
        r.w = plane[idx.w];
        *(float4*)(out + (size_t)b * nneg + n) = r;
    } else {
        for (int i = n; i < nneg; ++i)
            out[(size_t)b * nneg + i] = plane[neg[(size_t)b * nneg + i]];
    }
}

extern "C" void kernel_launch(void* const* d_in, const int* in_sizes, int n_in,
                              void* d_out, int out_size, void* d_ws, size_t ws_size,
                              hipStream_t stream) {
    const float* ent = (const float*)d_in[0];   // [100000, 256] f32
    const float* rel = (const float*)d_in[1];   // [500, 256]    f32
    const int*   pos = (const int*)d_in[2];     // [8, 3]        int32
    const int*   neg = (const int*)d_in[3];     // [8, 100000]   int32
    float* out = (float*)d_out;                 // [8, 100000]   f32

    const int nent = in_sizes[0] / HIDDEN;      // 100000
    const int nneg = in_sizes[3] / BATCH;       // 100000
    float* dist = (float*)d_ws;                 // 3.2 MB planar [8][nent]

    const int ngroups = nent / 8;               // 12500
    const int nblocks = 2048;                   // 8 blocks/CU, 32 waves/CU
    const int nwaves = nblocks * 4;
    kge_dist_kernel<<<nblocks, 256, 0, stream>>>(ent, rel, pos, dist,
                                                 ngroups, nent, nwaves);

    const int nquads = (nneg + 3) / 4;
    dim3 gridB((nquads + 255) / 256, BATCH);
    kge_gather_kernel<<<gridB, 256, 0, stream>>>(neg, dist, out, nneg, nent);
}

// Round 11
// 164.064 us; speedup vs baseline: 1.0317x; 1.0317x over previous
//
#include <hip/hip_runtime.h>

#define HIDDEN 256
#define GAMMA_F 12.0f
#define BATCH 8

// ---------------------------------------------------------------------------
// Kernel A: stream the entity table once — minimal-VGPR, max-TLP variant
// (best measured configuration; r9, total 163.6us).
// Lane covers dims [4*lane, 4*lane+4): one float4 load inst = one full 1KB
// row of unique contiguous data. Reduction: merge-tree — offsets 1,2,4 fold
// the 3 batch bits into lane bits 0..2, offsets 8,16,32 butterfly; lane l
// ends with the complete sum for batch l&7; lanes 0..7 store 32B contiguous.
// NOTE (session finding): five structurally different variants of this
// kernel (multi-row staging, pair-trees, LDS-DMA dbuf, register pipeline,
// 2x occupancy) all timed ~44-46us — the clamp is external to kernel
// structure (replay-regime memory backlog), so keep the simplest form.
// ---------------------------------------------------------------------------
__global__ __launch_bounds__(256, 8) void kge_dist_kernel(
    const float* __restrict__ ent,
    const float* __restrict__ rel,
    const int*  __restrict__ pos,
    float* __restrict__ dist,   // [nent, 8]
    int nent, int nwaves)
{
    const int lane = threadIdx.x & 63;
    const int wave_gid = (blockIdx.x * 256 + threadIdx.x) >> 6;

    // hr[b] = head_b + rel_b at dims [4*lane, 4*lane+4) — 32 VGPRs, once
    float4 hr[BATCH];
    #pragma unroll
    for (int b = 0; b < BATCH; ++b) {
        const int hidx = pos[b * 3 + 0];
        const int ridx = pos[b * 3 + 1];
        const float4 h4 = *(const float4*)(ent + (size_t)hidx * HIDDEN + lane * 4);
        const float4 r4 = *(const float4*)(rel + (size_t)ridx * HIDDEN + lane * 4);
        hr[b] = make_float4(h4.x + r4.x, h4.y + r4.y, h4.z + r4.z, h4.w + r4.w);
    }

    for (int e = wave_gid; e < nent; e += nwaves) {
        const float4 t4 = *(const float4*)(ent + (size_t)e * HIDDEN + lane * 4);

        float acc[BATCH];
        #pragma unroll
        for (int b = 0; b < BATCH; ++b) {
            acc[b] = fabsf(hr[b].x - t4.x) + fabsf(hr[b].y - t4.y)
                   + fabsf(hr[b].z - t4.z) + fabsf(hr[b].w - t4.w);
        }

        // fold batch bits into lane bits 0..2
        float v[4];
        {
            const bool p = lane & 1;
            #pragma unroll
            for (int k = 0; k < 4; ++k) {
                const float keep = p ? acc[2 * k + 1] : acc[2 * k];
                const float give = p ? acc[2 * k]     : acc[2 * k + 1];
                v[k] = keep + __shfl_xor(give, 1, 64);
            }
        }
        float w2[2];
        {
            const bool p = (lane >> 1) & 1;
            #pragma unroll
            for (int k = 0; k < 2; ++k) {
                const float keep = p ? v[2 * k + 1] : v[2 * k];
                const float give = p ? v[2 * k]     : v[2 * k + 1];
                w2[k] = keep + __shfl_xor(give, 2, 64);
            }
        }
        float s;
        {
            const bool p = (lane >> 2) & 1;
            const float keep = p ? w2[1] : w2[0];
            const float give = p ? w2[0] : w2[1];
            s = keep + __shfl_xor(give, 4, 64);
        }
        s += __shfl_xor(s, 8, 64);
        s += __shfl_xor(s, 16, 64);
        s += __shfl_xor(s, 32, 64);

        if (lane < BATCH)
            dist[(size_t)e * BATCH + lane] = GAMMA_F - s;
    }
}

// ---------------------------------------------------------------------------
// Kernel B: out[b,n] = dist[neg[b,n]*8 + b]. dist (3.2MB) is L2-resident.
// 2 outputs/thread: int2 index load, 2 independent gathers, float2 store.
// ---------------------------------------------------------------------------
__global__ __launch_bounds__(256) void kge_gather_kernel(
    const int*  __restrict__ neg,
    const float* __restrict__ dist,
    float* __restrict__ out,
    int nneg)
{
    const int b = blockIdx.y;
    const int n = (blockIdx.x * 256 + threadIdx.x) * 2;
    if (n + 1 < nneg) {
        const int2 idx = *(const int2*)(neg + (size_t)b * nneg + n);
        float2 r;
        r.x = dist[(size_t)idx.x * BATCH + b];
        r.y = dist[(size_t)idx.y * BATCH + b];
        *(float2*)(out + (size_t)b * nneg + n) = r;
    } else if (n < nneg) {
        out[(size_t)b * nneg + n] =
            dist[(size_t)neg[(size_t)b * nneg + n] * BATCH + b];
    }
}

extern "C" void kernel_launch(void* const* d_in, const int* in_sizes, int n_in,
                              void* d_out, int out_size, void* d_ws, size_t ws_size,
                              hipStream_t stream) {
    const float* ent = (const float*)d_in[0];   // [100000, 256] f32
    const float* rel = (const float*)d_in[1];   // [500, 256]    f32
    const int*   pos = (const int*)d_in[2];     // [8, 3]        int32
    const int*   neg = (const int*)d_in[3];     // [8, 100000]   int32
    float* out = (float*)d_out;                 // [8, 100000]   f32

    const int nent = in_sizes[0] / HIDDEN;      // 100000
    const int nneg = in_sizes[3] / BATCH;       // 100000
    float* dist = (float*)d_ws;                 // 3.2 MB (ws is larger)

    // 2048 blocks = 8 blocks/CU = 32 waves/CU (VGPR<=64 via bounds(256,8))
    const int nblocks = 2048;
    const int nwaves = nblocks * 4;
    kge_dist_kernel<<<nblocks, 256, 0, stream>>>(ent, rel, pos, dist,
                                                 nent, nwaves);

    const int npairs = (nneg + 1) / 2;
    dim3 gridB((npairs + 255) / 256, BATCH);
    kge_gather_kernel<<<gridB, 256, 0, stream>>>(neg, dist, out, nneg);
}